// Round 1
// 662.044 us; speedup vs baseline: 1.0786x; 1.0786x over previous
//
#include <hip/hip_runtime.h>
#include <math.h>

#define N_B 64
#define T_LEN 1024
#define IN_D 4
#define CH 5
#define SIG 780
#define KP 800           // padded K for f16 planes
#define SEG_LEN 16
#define N_SEG 64
// level offsets: L1:0, L2:5, L3:30, L4:155
#define SC_L1 1.0f
#define SC_L2 0.25f
#define SC_L3 0.0625f
#define SC_L4 0.015625f

typedef _Float16 f16x8 __attribute__((ext_vector_type(8)));
typedef float f32x4 __attribute__((ext_vector_type(4)));

typedef __attribute__((address_space(1))) const void* as1cp;
typedef __attribute__((address_space(3))) void* as3p;

#define VMCNT(n) asm volatile("s_waitcnt vmcnt(" #n ")" ::: "memory")

__device__ __forceinline__ float fast_tanh(float x) {
  float ax = fabsf(x);
  float e = __expf(-2.0f * ax);
  float r = (1.0f - e) * __builtin_amdgcn_rcpf(1.0f + e);
  return copysignf(r, x);
}

// ---------------- Kernel 1 (fallback only): time-aug + pointwise conv -------
__global__ __launch_bounds__(256) void conv_kernel(
    const float* __restrict__ batch,
    const float* __restrict__ conv_w,
    const float* __restrict__ conv_b,
    float* __restrict__ b_out) {
  int idx = blockIdx.x * blockDim.x + threadIdx.x;
  if (idx >= N_B * T_LEN) return;
  int t = idx & (T_LEN - 1);
  const float* a = batch + (size_t)idx * IN_D;
  float a0 = a[0], a1 = a[1], a2 = a[2], a3 = a[3];
  float tm = (float)(t + 1) / (float)T_LEN;
  float* o = b_out + (size_t)idx * CH;
#pragma unroll
  for (int j = 0; j < CH; ++j) {
    const float* w = conv_w + j * CH;
    float r = conv_b[j];
    r = fmaf(tm, w[4], r);
    r = fmaf(a3, w[3], r);
    r = fmaf(a2, w[2], r);
    r = fmaf(a1, w[1], r);
    r = fmaf(a0, w[0], r);
    o[j] = r;
  }
}

// ---------------- Signature phase A: per-segment signatures (conv fused) ----
__global__ __launch_bounds__(320) void seg_kernel(
    const float* __restrict__ batch,
    const float* __restrict__ conv_w,
    const float* __restrict__ conv_b,
    float* __restrict__ P) {
  int s = blockIdx.x;
  int n = blockIdx.y;
  int tid = threadIdx.x;

  __shared__ float S[SIG];
  __shared__ float bc[(SEG_LEN + 1) * CH];
  __shared__ float dsh[SEG_LEN][CH];

  for (int i = tid; i < SIG; i += 320) S[i] = 0.0f;
  if (tid < (SEG_LEN + 1) * CH) {
    int r = s * SEG_LEN - 1 + tid / CH, ch = tid % CH;
    float v = 0.0f;
    if (r >= 0) {
      const float* a = batch + ((size_t)n * T_LEN + r) * IN_D;
      const float* w = conv_w + ch * CH;
      v = conv_b[ch];
      v = fmaf(a[0], w[0], v);
      v = fmaf(a[1], w[1], v);
      v = fmaf(a[2], w[2], v);
      v = fmaf(a[3], w[3], v);
      v = fmaf((float)(r + 1) * (1.0f / T_LEN), w[4], v);
    }
    bc[tid] = v;
  }
  __syncthreads();
  if (tid < SEG_LEN * CH) {
    int j = tid / CH, ch = tid % CH;
    dsh[j][ch] = bc[(j + 1) * CH + ch] - bc[j * CH + ch];
  }

  const int x0 = tid;
  const int x1 = tid + 320;
  const bool has1 = (tid < 305);
  const int a0i = x0 / 125, b0i = (x0 / 25) % 5, c0i = (x0 / 5) % 5, d0i = x0 % 5;
  const int a1i = x1 / 125, b1i = (x1 / 25) % 5, c1i = (x1 / 5) % 5, d1i = x1 % 5;
  const int s2_0 = x0 / 25, s3_0 = x0 / 5;
  const int s2_1 = x1 / 25, s3_1 = x1 / 5;
  const bool hasL3 = (tid < 125);
  const int ya = tid / 25, yb = (tid / 5) % 5, yc = tid % 5;
  const bool hasL2 = (tid < 25);
  const int za = tid / 5, zb = tid % 5;
  const bool hasL1 = (tid < CH);
  __syncthreads();

  for (int j = 0; j < SEG_LEN; ++j) {
    float n4_0, n4_1 = 0.0f, n3 = 0.0f, n2 = 0.0f, n1 = 0.0f;
    {
      float tH = fmaf(0.25f, dsh[j][a0i], S[a0i]);
      tH = fmaf((1.0f / 3.0f) * dsh[j][b0i], tH, S[5 + s2_0]);
      tH = fmaf(0.5f * dsh[j][c0i], tH, S[30 + s3_0]);
      n4_0 = fmaf(dsh[j][d0i], tH, S[155 + x0]);
    }
    if (has1) {
      float tH = fmaf(0.25f, dsh[j][a1i], S[a1i]);
      tH = fmaf((1.0f / 3.0f) * dsh[j][b1i], tH, S[5 + s2_1]);
      tH = fmaf(0.5f * dsh[j][c1i], tH, S[30 + s3_1]);
      n4_1 = fmaf(dsh[j][d1i], tH, S[155 + x1]);
    }
    if (hasL3) {
      float tH = fmaf((1.0f / 3.0f), dsh[j][ya], S[ya]);
      tH = fmaf(0.5f * dsh[j][yb], tH, S[5 + ya * 5 + yb]);
      n3 = fmaf(dsh[j][yc], tH, S[30 + tid]);
    }
    if (hasL2) {
      float tH = fmaf(0.5f, dsh[j][za], S[za]);
      n2 = fmaf(dsh[j][zb], tH, S[5 + tid]);
    }
    if (hasL1) n1 = S[tid] + dsh[j][tid];
    __syncthreads();
    S[155 + x0] = n4_0;
    if (has1) S[155 + x1] = n4_1;
    if (hasL3) S[30 + tid] = n3;
    if (hasL2) S[5 + tid] = n2;
    if (hasL1) S[tid] = n1;
    __syncthreads();
  }

  float* Pr = P + ((size_t)n * N_SEG + s) * SIG;
  for (int i = tid; i < SIG; i += 320) Pr[i] = S[i];
}

// ---------------- Signature phase B: sequential prefix (reg-prefetched) -----
__global__ __launch_bounds__(640) void prefix_kernel(float* __restrict__ P) {
  int n = blockIdx.x;
  int tid = threadIdx.x;
  __shared__ float A[SIG];
  __shared__ float Bs[SIG];

  float* Pn = P + (size_t)n * N_SEG * SIG;
  for (int i = tid; i < SIG; i += 640) A[i] = Pn[i];
  int i0 = tid, i1 = tid + 640;
  float r0 = 0.f, r1 = 0.f;
  if (i0 < SIG) r0 = Pn[SIG + i0];
  if (i1 < SIG) r1 = Pn[SIG + i1];

  const int e4 = tid;
  const int q4a = e4 / 125, r125 = e4 % 125, r25 = e4 % 25, r5 = e4 % 5;
  const int e4d5 = e4 / 5, e4d25 = e4 / 25;
  const int e3 = tid;
  const int e3a = e3 / 25, e3r25 = e3 % 25, e3r5 = e3 % 5, e3d5 = e3 / 5;
  const int e2 = tid - 125;
  const int e1 = tid - 150;

  for (int s = 1; s < N_SEG; ++s) {
    if (i0 < SIG) Bs[i0] = r0;
    if (i1 < SIG) Bs[i1] = r1;
    __syncthreads();
    if (s + 1 < N_SEG) {
      const float* Pnx = Pn + (size_t)(s + 1) * SIG;
      if (i0 < SIG) r0 = Pnx[i0];
      if (i1 < SIG) r1 = Pnx[i1];
    }
    float v4 = 0.f, v3 = 0.f, v2 = 0.f, v1 = 0.f;
    if (tid < 625) {
      v4 = A[155 + e4] + Bs[155 + e4];
      v4 = fmaf(A[30 + e4d5], Bs[r5], v4);
      v4 = fmaf(A[5 + e4d25], Bs[5 + r25], v4);
      v4 = fmaf(A[q4a], Bs[30 + r125], v4);
    }
    if (tid < 125) {
      v3 = A[30 + e3] + Bs[30 + e3];
      v3 = fmaf(A[5 + e3d5], Bs[e3r5], v3);
      v3 = fmaf(A[e3a], Bs[5 + e3r25], v3);
    } else if (tid < 150) {
      v2 = A[5 + e2] + Bs[5 + e2];
      v2 = fmaf(A[e2 / 5], Bs[e2 % 5], v2);
    } else if (tid < 155) {
      v1 = A[e1] + Bs[e1];
    }
    __syncthreads();
    float* Po = Pn + (size_t)s * SIG;
    if (tid < 625) { A[155 + e4] = v4; Po[155 + e4] = v4; }
    if (tid < 125) { A[30 + e3] = v3; Po[30 + e3] = v3; }
    else if (tid < 150) { A[5 + e2] = v2; Po[5 + e2] = v2; }
    else if (tid < 155) { A[e1] = v1; Po[e1] = v1; }
  }
}

// ---------------- Signature phase C: stream + emit f16 planes (coalesced) ---
__global__ __launch_bounds__(320) void emit_kernel(
    const float* __restrict__ batch,
    const float* __restrict__ conv_w,
    const float* __restrict__ conv_b,
    const float* __restrict__ P,
    _Float16* __restrict__ c1,
    _Float16* __restrict__ c2) {
  int s = blockIdx.x;
  int n = blockIdx.y;
  int tid = threadIdx.x;

  __shared__ float S[SIG];
  __shared__ float bc[(SEG_LEN + 1) * CH];
  __shared__ float dsh[SEG_LEN][CH];
  __shared__ __align__(16) _Float16 row1[KP];
  __shared__ __align__(16) _Float16 row2[KP];

  if (s == 0) {
    for (int i = tid; i < SIG; i += 320) S[i] = 0.0f;
  } else {
    const float* Pr = P + ((size_t)n * N_SEG + (s - 1)) * SIG;
    for (int i = tid; i < SIG; i += 320) S[i] = Pr[i];
  }
  if (tid < (SEG_LEN + 1) * CH) {
    int r = s * SEG_LEN - 1 + tid / CH, ch = tid % CH;
    float v = 0.0f;
    if (r >= 0) {
      const float* a = batch + ((size_t)n * T_LEN + r) * IN_D;
      const float* w = conv_w + ch * CH;
      v = conv_b[ch];
      v = fmaf(a[0], w[0], v);
      v = fmaf(a[1], w[1], v);
      v = fmaf(a[2], w[2], v);
      v = fmaf(a[3], w[3], v);
      v = fmaf((float)(r + 1) * (1.0f / T_LEN), w[4], v);
    }
    bc[tid] = v;
  }
  if (tid < KP - SIG) {  // zero the pad tail once
    row1[SIG + tid] = (_Float16)0.0f;
    row2[SIG + tid] = (_Float16)0.0f;
  }
  __syncthreads();
  if (tid < SEG_LEN * CH) {
    int j = tid / CH, ch = tid % CH;
    dsh[j][ch] = bc[(j + 1) * CH + ch] - bc[j * CH + ch];
  }

  const int x0 = tid;
  const int x1 = tid + 320;
  const bool has1 = (tid < 305);
  const int a0i = x0 / 125, b0i = (x0 / 25) % 5, c0i = (x0 / 5) % 5, d0i = x0 % 5;
  const int a1i = x1 / 125, b1i = (x1 / 25) % 5, c1i = (x1 / 5) % 5, d1i = x1 % 5;
  const int s2_0 = x0 / 25, s3_0 = x0 / 5;
  const int s2_1 = x1 / 25, s3_1 = x1 / 5;
  const bool hasL3 = (tid < 125);
  const int ya = tid / 25, yb = (tid / 5) % 5, yc = tid % 5;
  const bool hasL2 = (tid < 25);
  const int za = tid / 5, zb = tid % 5;
  const bool hasL1 = (tid < CH);
  __syncthreads();

  for (int j = 0; j < SEG_LEN; ++j) {
    int t = s * SEG_LEN + j;
    float n4_0, n4_1 = 0.0f, n3 = 0.0f, n2 = 0.0f, n1 = 0.0f;
    {
      float tH = fmaf(0.25f, dsh[j][a0i], S[a0i]);
      tH = fmaf((1.0f / 3.0f) * dsh[j][b0i], tH, S[5 + s2_0]);
      tH = fmaf(0.5f * dsh[j][c0i], tH, S[30 + s3_0]);
      n4_0 = fmaf(dsh[j][d0i], tH, S[155 + x0]);
    }
    if (has1) {
      float tH = fmaf(0.25f, dsh[j][a1i], S[a1i]);
      tH = fmaf((1.0f / 3.0f) * dsh[j][b1i], tH, S[5 + s2_1]);
      tH = fmaf(0.5f * dsh[j][c1i], tH, S[30 + s3_1]);
      n4_1 = fmaf(dsh[j][d1i], tH, S[155 + x1]);
    }
    if (hasL3) {
      float tH = fmaf((1.0f / 3.0f), dsh[j][ya], S[ya]);
      tH = fmaf(0.5f * dsh[j][yb], tH, S[5 + ya * 5 + yb]);
      n3 = fmaf(dsh[j][yc], tH, S[30 + tid]);
    }
    if (hasL2) {
      float tH = fmaf(0.5f, dsh[j][za], S[za]);
      n2 = fmaf(dsh[j][zb], tH, S[5 + tid]);
    }
    if (hasL1) n1 = S[tid] + dsh[j][tid];
    __syncthreads();

    S[155 + x0] = n4_0;
    if (has1) S[155 + x1] = n4_1;
    if (hasL3) S[30 + tid] = n3;
    if (hasL2) S[5 + tid] = n2;
    if (hasL1) S[tid] = n1;

    float z = (t == 0) ? 0.0f : 1.0f;
    {
      float v = n4_0 * SC_L4 * z;
      _Float16 h = (_Float16)v;
      row1[155 + x0] = h; row2[155 + x0] = (_Float16)(v - (float)h);
    }
    if (has1) {
      float v = n4_1 * SC_L4 * z;
      _Float16 h = (_Float16)v;
      row1[155 + x1] = h; row2[155 + x1] = (_Float16)(v - (float)h);
    }
    if (hasL3) {
      float v = n3 * SC_L3 * z;
      _Float16 h = (_Float16)v;
      row1[30 + tid] = h; row2[30 + tid] = (_Float16)(v - (float)h);
    }
    if (hasL2) {
      float v = n2 * SC_L2 * z;
      _Float16 h = (_Float16)v;
      row1[5 + tid] = h; row2[5 + tid] = (_Float16)(v - (float)h);
    }
    if (hasL1) {
      float v = n1 * SC_L1 * z;
      _Float16 h = (_Float16)v;
      row1[tid] = h; row2[tid] = (_Float16)(v - (float)h);
    }
    __syncthreads();

    size_t base = ((size_t)n * T_LEN + t) * KP;
    if (tid < 100) {
      *(float4*)(c1 + base + tid * 8) = *(const float4*)&row1[tid * 8];
    } else if (tid < 200) {
      int c = tid - 100;
      *(float4*)(c2 + base + c * 8) = *(const float4*)&row2[c * 8];
    }
  }
}

// ---------------- W plane conversion (scaled, padded to 896x800) -------------
__global__ __launch_bounds__(256) void wconv_kernel(
    const float* __restrict__ W,
    _Float16* __restrict__ w1,
    _Float16* __restrict__ w2) {
  int idx = blockIdx.x * blockDim.x + threadIdx.x;
  if (idx >= 896 * KP) return;
  int nn = idx / KP, k = idx % KP;
  float v = 0.0f;
  if (nn < SIG && k < SIG) {
    float sc = (k < 5) ? 1.0f : (k < 30) ? 4.0f : (k < 155) ? 16.0f : 64.0f;
    v = W[(size_t)nn * SIG + k] * sc;
  }
  _Float16 h = (_Float16)v;
  w1[idx] = h;
  w2[idx] = (_Float16)(v - (float)h);
}

// ---------------- MFMA GEMM: out = tanh((c1+c2)*(w1+w2)^T + b) ---------------
// 256x128 block tile, 8 waves (4m x 2n), per-wave 64x64 = 4x4 of 16x16x32_f16,
// 3 products (hi*hi, hi*lo, lo*hi).
// Schedule: 3 LDS buffers (144 KB), prefetch depth 2, counted vmcnt(6) once
// per K-step (loads stay in flight across barriers), 2 phases per K-step each
// {ds_read frags || issue global_load_lds for tile k+2; s_barrier;
//  setprio(1); 24 MFMA; setprio(0)}. XCD-bijective block swizzle: the 7
// n-tile siblings of each m-tile land on the same XCD (A fetched ~once/HBM).
__global__ __launch_bounds__(512, 2) void gemm_mfma(
    const _Float16* __restrict__ A1p, const _Float16* __restrict__ A2p,
    const _Float16* __restrict__ B1p, const _Float16* __restrict__ B2p,
    const float* __restrict__ bias, float* __restrict__ out) {
  __shared__ _Float16 Al[3][2][256 * 32];  // [buf][plane] : 96 KB
  __shared__ _Float16 Bl[3][2][128 * 32];  // [buf][plane] : 48 KB

  int tid = threadIdx.x;
  int lane = tid & 63, wid = tid >> 6;
  int wm = wid >> 1, wn = wid & 1;

  // XCD-bijective swizzle: hw assigns xcd = blockIdx % 8 (round-robin).
  // 1792 blocks = 8 xcd * 224; per-xcd slot s -> m-tile (s/7)*8+xcd, n = s%7.
  int b = blockIdx.x;
  int xcd = b & 7, sidx = b >> 3;
  int mt = (sidx / 7) * 8 + xcd;
  int nt = sidx % 7;
  int m0 = mt * 256;
  int n0 = nt * 128;

  f32x4 acc[4][4];
#pragma unroll
  for (int i = 0; i < 4; ++i)
#pragma unroll
    for (int j = 0; j < 4; ++j) acc[i][j] = (f32x4){0.f, 0.f, 0.f, 0.f};

  int sr = lane >> 2, scn = lane & 3;
  int swst = (sr ^ (sr >> 2)) & 3;
  int qg = scn ^ swst;          // pre-swizzled global chunk (LDS stays linear)
  int fr = lane & 15, fq = lane >> 4;
  int swf = (fr ^ (fr >> 2)) & 3;
  int fchunk = fq ^ swf;        // matching read-side swizzle

  // staging: per thread per K-tile, 4 A-loads + 2 B-loads (16 B each).
  auto stageA = [&](int kb, int buf, int i) {
    int k0 = kb * 32;
    int linear = wid * 4 + i;          // 0..31
    int plane = linear >> 4, grp = linear & 15;
    size_t g = (size_t)(m0 + grp * 16 + sr) * KP + k0 + qg * 8;
    const _Float16* src = (plane ? A2p : A1p) + g;
    __builtin_amdgcn_global_load_lds((as1cp)src, (as3p)(&Al[buf][plane][grp * 512]), 16, 0, 0);
  };
  auto stageB = [&](int kb, int buf, int i) {
    int k0 = kb * 32;
    int linear = wid * 2 + i;          // 0..15
    int plane = linear >> 3, grp = linear & 7;
    size_t g = (size_t)(n0 + grp * 16 + sr) * KP + k0 + qg * 8;
    const _Float16* src = (plane ? B2p : B1p) + g;
    __builtin_amdgcn_global_load_lds((as1cp)src, (as3p)(&Bl[buf][plane][grp * 512]), 16, 0, 0);
  };

  // prologue: tiles 0 and 1 in flight (12 loads/thread)
#pragma unroll
  for (int i = 0; i < 4; ++i) stageA(0, 0, i);
#pragma unroll
  for (int i = 0; i < 2; ++i) stageB(0, 0, i);
#pragma unroll
  for (int i = 0; i < 4; ++i) stageA(1, 1, i);
#pragma unroll
  for (int i = 0; i < 2; ++i) stageB(1, 1, i);

  f16x8 b1f[4], b2f[4];
  int cur = 0;
#pragma unroll 1
  for (int kb = 0; kb < 25; ++kb) {
    int nx = cur + 2; if (nx >= 3) nx -= 3;
    bool pf = (kb + 2 < 25);
    // counted wait: tile kb done, tile kb+1's 6 loads stay in flight
    if (kb < 24) { VMCNT(6); } else { VMCNT(0); }
    __builtin_amdgcn_s_barrier();
    __builtin_amdgcn_sched_barrier(0);
#pragma unroll
    for (int ph = 0; ph < 2; ++ph) {
      f16x8 a1f[2], a2f[2];
      if (ph == 0) {
#pragma unroll
        for (int tn = 0; tn < 4; ++tn) {
          int off = (wn * 64 + tn * 16 + fr) * 32 + fchunk * 8;
          b1f[tn] = *(const f16x8*)&Bl[cur][0][off];
          b2f[tn] = *(const f16x8*)&Bl[cur][1][off];
        }
      }
#pragma unroll
      for (int t = 0; t < 2; ++t) {
        int tm = ph * 2 + t;
        int off = (wm * 64 + tm * 16 + fr) * 32 + fchunk * 8;
        a1f[t] = *(const f16x8*)&Al[cur][0][off];
        a2f[t] = *(const f16x8*)&Al[cur][1][off];
      }
      if (pf) {  // issue next-next tile loads; they ride across barriers
        stageA(kb + 2, nx, ph * 2 + 0);
        stageA(kb + 2, nx, ph * 2 + 1);
        stageB(kb + 2, nx, ph);
      }
      __builtin_amdgcn_s_barrier();
      __builtin_amdgcn_sched_barrier(0);
      __builtin_amdgcn_s_setprio(1);
#pragma unroll
      for (int t = 0; t < 2; ++t) {
        int tm = ph * 2 + t;
#pragma unroll
        for (int tn = 0; tn < 4; ++tn) {
          acc[tm][tn] = __builtin_amdgcn_mfma_f32_16x16x32_f16(a1f[t], b1f[tn], acc[tm][tn], 0, 0, 0);
          acc[tm][tn] = __builtin_amdgcn_mfma_f32_16x16x32_f16(a1f[t], b2f[tn], acc[tm][tn], 0, 0, 0);
          acc[tm][tn] = __builtin_amdgcn_mfma_f32_16x16x32_f16(a2f[t], b1f[tn], acc[tm][tn], 0, 0, 0);
        }
      }
      __builtin_amdgcn_s_setprio(0);
    }
    cur = cur + 1; if (cur >= 3) cur -= 3;
  }
  __syncthreads();  // all frag reads done; LDS reusable for epilogue

  // epilogue: bias + fast tanh, per-wave LDS transpose, float4 stores
  float* ep = (float*)(&Al[0][0][0]) + wid * 2112;  // 32x66 f32 per wave

  float bv[4];
#pragma unroll
  for (int tn = 0; tn < 4; ++tn) {
    int nn = n0 + wn * 64 + tn * 16 + fr;
    bv[tn] = (nn < SIG) ? bias[nn] : 0.0f;
  }
#pragma unroll
  for (int h = 0; h < 2; ++h) {
#pragma unroll
    for (int tm2 = 0; tm2 < 2; ++tm2) {
      int tm = h * 2 + tm2;
#pragma unroll
      for (int tn = 0; tn < 4; ++tn) {
#pragma unroll
        for (int r = 0; r < 4; ++r) {
          int lr = tm2 * 16 + fq * 4 + r;  // 0..31
          int lc = tn * 16 + fr;           // 0..63
          ep[lr * 66 + lc] = fast_tanh(acc[tm][tn][r] + bv[tn]);
        }
      }
    }
    // wave-synchronous readout: 32 rows x 64 cols, float4 per 4 cols
#pragma unroll
    for (int p = 0; p < 2; ++p) {
      int lr = lane & 31;
      int ck = (lane >> 5) * 2 + p;  // 0..3 (16-col chunk)
      int gm = m0 + wm * 64 + h * 32 + lr;
      int gc0 = n0 + wn * 64 + ck * 16;
#pragma unroll
      for (int q = 0; q < 4; ++q) {
        int col = gc0 + q * 4;
        if (col + 3 < SIG) {
          *(float4*)(out + (size_t)gm * SIG + col) =
              *(const float4*)&ep[lr * 66 + ck * 16 + q * 4];
        } else if (col < SIG) {
#pragma unroll
          for (int e = 0; e < 4; ++e) {
            int c2 = col + e;
            if (c2 < SIG) out[(size_t)gm * SIG + c2] = ep[lr * 66 + ck * 16 + q * 4 + e];
          }
        }
      }
    }
  }
}

// ================= FALLBACK PATH (round-1, fp32) =============================
__global__ __launch_bounds__(320) void sig_kernel_fb(
    const float* __restrict__ b_in, float* __restrict__ c_out) {
  int n = blockIdx.x;
  int tid = threadIdx.x;
  __shared__ float S[SIG];
  __shared__ float bc[64 * CH];
  __shared__ float dsh[CH];
  __shared__ float pb[CH];
  for (int i = tid; i < SIG; i += 320) S[i] = 0.0f;
  if (tid < CH) pb[tid] = 0.0f;
  const float* bn = b_in + (size_t)n * T_LEN * CH;
  float* cn = c_out + (size_t)n * T_LEN * SIG;
  const int x0 = tid, x1 = tid + 320;
  const bool has1 = (tid < 305);
  const int a0i = x0 / 125, b0i = (x0 / 25) % 5, c0i = (x0 / 5) % 5, d0i = x0 % 5;
  const int a1i = x1 / 125, b1i = (x1 / 25) % 5, c1i = (x1 / 5) % 5, d1i = x1 % 5;
  const int s2_0 = x0 / 25, s3_0 = x0 / 5, s2_1 = x1 / 25, s3_1 = x1 / 5;
  const bool hasL3 = (tid < 125);
  const int ya = tid / 25, yb = (tid / 5) % 5, yc = tid % 5;
  const bool hasL2 = (tid < 25);
  const int za = tid / 5, zb = tid % 5;
  const bool hasL1 = (tid < CH);
  for (int t = 0; t < T_LEN; ++t) {
    if ((t & 63) == 0) {
      __syncthreads();
      bc[tid] = bn[t * CH + tid];
      __syncthreads();
    }
    if (tid < CH) {
      float cur = bc[(t & 63) * CH + tid];
      dsh[tid] = cur - pb[tid];
      pb[tid] = cur;
    }
    __syncthreads();
    float n4_0, n4_1 = 0.0f, n3 = 0.0f, n2 = 0.0f, n1 = 0.0f;
    {
      float tH = fmaf(0.25f, dsh[a0i], S[a0i]);
      tH = fmaf((1.0f / 3.0f) * dsh[b0i], tH, S[5 + s2_0]);
      tH = fmaf(0.5f * dsh[c0i], tH, S[30 + s3_0]);
      n4_0 = fmaf(dsh[d0i], tH, S[155 + x0]);
    }
    if (has1) {
      float tH = fmaf(0.25f, dsh[a1i], S[a1i]);
      tH = fmaf((1.0f / 3.0f) * dsh[b1i], tH, S[5 + s2_1]);
      tH = fmaf(0.5f * dsh[c1i], tH, S[30 + s3_1]);
      n4_1 = fmaf(dsh[d1i], tH, S[155 + x1]);
    }
    if (hasL3) {
      float tH = fmaf((1.0f / 3.0f), dsh[ya], S[ya]);
      tH = fmaf(0.5f * dsh[yb], tH, S[5 + ya * 5 + yb]);
      n3 = fmaf(dsh[yc], tH, S[30 + tid]);
    }
    if (hasL2) {
      float tH = fmaf(0.5f, dsh[za], S[za]);
      n2 = fmaf(dsh[zb], tH, S[5 + tid]);
    }
    if (hasL1) n1 = S[tid] + dsh[tid];
    __syncthreads();
    S[155 + x0] = n4_0;
    if (has1) S[155 + x1] = n4_1;
    if (hasL3) S[30 + tid] = n3;
    if (hasL2) S[5 + tid] = n2;
    if (hasL1) S[tid] = n1;
    float* crow = cn + (size_t)t * SIG;
    float z = (t == 0) ? 0.0f : 1.0f;
    crow[155 + x0] = n4_0 * z;
    if (has1) crow[155 + x1] = n4_1 * z;
    if (hasL3) crow[30 + tid] = n3 * z;
    if (hasL2) crow[5 + tid] = n2 * z;
    if (hasL1) crow[tid] = n1 * z;
    __syncthreads();
  }
}

#define BM 256
#define BN 64
#define BK 16
__global__ __launch_bounds__(256) void gemm_tanh_fb(
    const float* __restrict__ Cmat, const float* __restrict__ W,
    const float* __restrict__ bias, float* __restrict__ out) {
  __shared__ float As[BK][BM + 4];
  __shared__ float Ws[BK][BN + 4];
  int tid = threadIdx.x;
  int tx = tid & 7, ty = tid >> 3;
  int m0 = blockIdx.x * BM, n0 = blockIdx.y * BN;
  float acc[8][8];
#pragma unroll
  for (int i = 0; i < 8; ++i)
#pragma unroll
    for (int j = 0; j < 8; ++j) acc[i][j] = 0.0f;
  for (int kb = 0; kb < SIG; kb += BK) {
    __syncthreads();
#pragma unroll
    for (int p = 0; p < 4; ++p) {
      int id = tid + p * 256;
      int row = id >> 2, kg = (id & 3) * 4, gk = kb + kg;
      float4 v = make_float4(0.f, 0.f, 0.f, 0.f);
      if (gk < SIG) v = *(const float4*)(Cmat + (size_t)(m0 + row) * SIG + gk);
      As[kg + 0][row] = v.x; As[kg + 1][row] = v.y;
      As[kg + 2][row] = v.z; As[kg + 3][row] = v.w;
    }
    {
      int row = tid >> 2, kg = (tid & 3) * 4, gk = kb + kg, wr = n0 + row;
      float4 v = make_float4(0.f, 0.f, 0.f, 0.f);
      if (gk < SIG && wr < SIG) v = *(const float4*)(W + (size_t)wr * SIG + gk);
      Ws[kg + 0][row] = v.x; Ws[kg + 1][row] = v.y;
      Ws[kg + 2][row] = v.z; Ws[kg + 3][row] = v.w;
    }
    __syncthreads();
#pragma unroll
    for (int k = 0; k < BK; ++k) {
      float af[8], wf[8];
      *(float4*)&af[0] = *(const float4*)&As[k][ty * 8];
      *(float4*)&af[4] = *(const float4*)&As[k][ty * 8 + 4];
      *(float4*)&wf[0] = *(const float4*)&Ws[k][tx * 8];
      *(float4*)&wf[4] = *(const float4*)&Ws[k][tx * 8 + 4];
#pragma unroll
      for (int i = 0; i < 8; ++i)
#pragma unroll
        for (int j = 0; j < 8; ++j) acc[i][j] = fmaf(af[i], wf[j], acc[i][j]);
    }
  }
#pragma unroll
  for (int i = 0; i < 8; ++i) {
    int m = m0 + ty * 8 + i;
    float* orow = out + (size_t)m * SIG;
#pragma unroll
    for (int jj = 0; jj < 8; jj += 4) {
      int col = n0 + tx * 8 + jj;
      if (col < SIG) {
        float4 r;
        r.x = tanhf(acc[i][jj + 0] + bias[col + 0]);
        r.y = tanhf(acc[i][jj + 1] + bias[col + 1]);
        r.z = tanhf(acc[i][jj + 2] + bias[col + 2]);
        r.w = tanhf(acc[i][jj + 3] + bias[col + 3]);
        *(float4*)(orow + col) = r;
      }
    }
  }
}

// ---------------- launch ----------------
extern "C" void kernel_launch(void* const* d_in, const int* in_sizes, int n_in,
                              void* d_out, int out_size, void* d_ws, size_t ws_size,
                              hipStream_t stream) {
  const float* batch = (const float*)d_in[0];
  const float* conv_w = (const float*)d_in[1];
  const float* conv_b = (const float*)d_in[2];
  const float* lin_w = (const float*)d_in[3];
  const float* lin_b = (const float*)d_in[4];
  float* out = (float*)d_out;

  const size_t plane_elems = (size_t)N_B * T_LEN * KP;        // 52,428,800
  const size_t wplane_elems = (size_t)896 * KP;               // 716,800
  const size_t P_elems = (size_t)N_B * N_SEG * SIG;           // 3,194,880
  const size_t bp_elems = (size_t)N_B * T_LEN * CH;           // 327,680
  const size_t need_big = 2 * plane_elems * sizeof(_Float16) +
                          2 * wplane_elems * sizeof(_Float16) +
                          P_elems * sizeof(float);

  if (ws_size >= need_big) {
    _Float16* c1 = (_Float16*)d_ws;
    _Float16* c2 = c1 + plane_elems;
    _Float16* w1 = c2 + plane_elems;
    _Float16* w2 = w1 + wplane_elems;
    float* P = (float*)(w2 + wplane_elems);

    wconv_kernel<<<dim3((896 * KP + 255) / 256), dim3(256), 0, stream>>>(
        lin_w, w1, w2);
    seg_kernel<<<dim3(N_SEG, N_B), dim3(320), 0, stream>>>(batch, conv_w, conv_b, P);
    prefix_kernel<<<dim3(N_B), dim3(640), 0, stream>>>(P);
    emit_kernel<<<dim3(N_SEG, N_B), dim3(320), 0, stream>>>(
        batch, conv_w, conv_b, P, c1, c2);
    gemm_mfma<<<dim3(1792), dim3(512), 0, stream>>>(c1, c2, w1, w2, lin_b, out);
  } else {
    float* b_path = (float*)d_ws;
    float* c_sig = (float*)d_ws + bp_elems;
    conv_kernel<<<dim3((N_B * T_LEN + 255) / 256), dim3(256), 0, stream>>>(
        batch, conv_w, conv_b, b_path);
    sig_kernel_fb<<<dim3(N_B), dim3(320), 0, stream>>>(b_path, c_sig);
    gemm_tanh_fb<<<dim3((N_B * T_LEN) / BM, (SIG + BN - 1) / BN), dim3(256), 0, stream>>>(
        c_sig, lin_w, lin_b, out);
  }
}

// Round 2
// 660.786 us; speedup vs baseline: 1.0806x; 1.0019x over previous
//
#include <hip/hip_runtime.h>
#include <math.h>

#define N_B 64
#define T_LEN 1024
#define IN_D 4
#define CH 5
#define SIG 780
#define KP 800           // padded K for f16 planes
#define SEG_LEN 16
#define N_SEG 64
// level offsets: L1:0, L2:5, L3:30, L4:155
#define SC_L1 1.0f
#define SC_L2 0.25f
#define SC_L3 0.0625f
#define SC_L4 0.015625f

typedef _Float16 f16x8 __attribute__((ext_vector_type(8)));
typedef float f32x4 __attribute__((ext_vector_type(4)));

typedef __attribute__((address_space(1))) const void* as1cp;
typedef __attribute__((address_space(3))) void* as3p;

#define VMCNT(n) asm volatile("s_waitcnt vmcnt(" #n ")" ::: "memory")

__device__ __forceinline__ float fast_tanh(float x) {
  float ax = fabsf(x);
  float e = __expf(-2.0f * ax);
  float r = (1.0f - e) * __builtin_amdgcn_rcpf(1.0f + e);
  return copysignf(r, x);
}

// ---------------- Kernel 1 (fallback only): time-aug + pointwise conv -------
__global__ __launch_bounds__(256) void conv_kernel(
    const float* __restrict__ batch,
    const float* __restrict__ conv_w,
    const float* __restrict__ conv_b,
    float* __restrict__ b_out) {
  int idx = blockIdx.x * blockDim.x + threadIdx.x;
  if (idx >= N_B * T_LEN) return;
  int t = idx & (T_LEN - 1);
  const float* a = batch + (size_t)idx * IN_D;
  float a0 = a[0], a1 = a[1], a2 = a[2], a3 = a[3];
  float tm = (float)(t + 1) / (float)T_LEN;
  float* o = b_out + (size_t)idx * CH;
#pragma unroll
  for (int j = 0; j < CH; ++j) {
    const float* w = conv_w + j * CH;
    float r = conv_b[j];
    r = fmaf(tm, w[4], r);
    r = fmaf(a3, w[3], r);
    r = fmaf(a2, w[2], r);
    r = fmaf(a1, w[1], r);
    r = fmaf(a0, w[0], r);
    o[j] = r;
  }
}

// ---------------- Signature phase A: per-segment signatures (conv fused) ----
__global__ __launch_bounds__(320) void seg_kernel(
    const float* __restrict__ batch,
    const float* __restrict__ conv_w,
    const float* __restrict__ conv_b,
    float* __restrict__ P) {
  int s = blockIdx.x;
  int n = blockIdx.y;
  int tid = threadIdx.x;

  __shared__ float S[SIG];
  __shared__ float bc[(SEG_LEN + 1) * CH];
  __shared__ float dsh[SEG_LEN][CH];

  for (int i = tid; i < SIG; i += 320) S[i] = 0.0f;
  if (tid < (SEG_LEN + 1) * CH) {
    int r = s * SEG_LEN - 1 + tid / CH, ch = tid % CH;
    float v = 0.0f;
    if (r >= 0) {
      const float* a = batch + ((size_t)n * T_LEN + r) * IN_D;
      const float* w = conv_w + ch * CH;
      v = conv_b[ch];
      v = fmaf(a[0], w[0], v);
      v = fmaf(a[1], w[1], v);
      v = fmaf(a[2], w[2], v);
      v = fmaf(a[3], w[3], v);
      v = fmaf((float)(r + 1) * (1.0f / T_LEN), w[4], v);
    }
    bc[tid] = v;
  }
  __syncthreads();
  if (tid < SEG_LEN * CH) {
    int j = tid / CH, ch = tid % CH;
    dsh[j][ch] = bc[(j + 1) * CH + ch] - bc[j * CH + ch];
  }

  const int x0 = tid;
  const int x1 = tid + 320;
  const bool has1 = (tid < 305);
  const int a0i = x0 / 125, b0i = (x0 / 25) % 5, c0i = (x0 / 5) % 5, d0i = x0 % 5;
  const int a1i = x1 / 125, b1i = (x1 / 25) % 5, c1i = (x1 / 5) % 5, d1i = x1 % 5;
  const int s2_0 = x0 / 25, s3_0 = x0 / 5;
  const int s2_1 = x1 / 25, s3_1 = x1 / 5;
  const bool hasL3 = (tid < 125);
  const int ya = tid / 25, yb = (tid / 5) % 5, yc = tid % 5;
  const bool hasL2 = (tid < 25);
  const int za = tid / 5, zb = tid % 5;
  const bool hasL1 = (tid < CH);
  __syncthreads();

  for (int j = 0; j < SEG_LEN; ++j) {
    float n4_0, n4_1 = 0.0f, n3 = 0.0f, n2 = 0.0f, n1 = 0.0f;
    {
      float tH = fmaf(0.25f, dsh[j][a0i], S[a0i]);
      tH = fmaf((1.0f / 3.0f) * dsh[j][b0i], tH, S[5 + s2_0]);
      tH = fmaf(0.5f * dsh[j][c0i], tH, S[30 + s3_0]);
      n4_0 = fmaf(dsh[j][d0i], tH, S[155 + x0]);
    }
    if (has1) {
      float tH = fmaf(0.25f, dsh[j][a1i], S[a1i]);
      tH = fmaf((1.0f / 3.0f) * dsh[j][b1i], tH, S[5 + s2_1]);
      tH = fmaf(0.5f * dsh[j][c1i], tH, S[30 + s3_1]);
      n4_1 = fmaf(dsh[j][d1i], tH, S[155 + x1]);
    }
    if (hasL3) {
      float tH = fmaf((1.0f / 3.0f), dsh[j][ya], S[ya]);
      tH = fmaf(0.5f * dsh[j][yb], tH, S[5 + ya * 5 + yb]);
      n3 = fmaf(dsh[j][yc], tH, S[30 + tid]);
    }
    if (hasL2) {
      float tH = fmaf(0.5f, dsh[j][za], S[za]);
      n2 = fmaf(dsh[j][zb], tH, S[5 + tid]);
    }
    if (hasL1) n1 = S[tid] + dsh[j][tid];
    __syncthreads();
    S[155 + x0] = n4_0;
    if (has1) S[155 + x1] = n4_1;
    if (hasL3) S[30 + tid] = n3;
    if (hasL2) S[5 + tid] = n2;
    if (hasL1) S[tid] = n1;
    __syncthreads();
  }

  float* Pr = P + ((size_t)n * N_SEG + s) * SIG;
  for (int i = tid; i < SIG; i += 320) Pr[i] = S[i];
}

// ---------------- Signature phase B: sequential prefix (reg-prefetched) -----
__global__ __launch_bounds__(640) void prefix_kernel(float* __restrict__ P) {
  int n = blockIdx.x;
  int tid = threadIdx.x;
  __shared__ float A[SIG];
  __shared__ float Bs[SIG];

  float* Pn = P + (size_t)n * N_SEG * SIG;
  for (int i = tid; i < SIG; i += 640) A[i] = Pn[i];
  int i0 = tid, i1 = tid + 640;
  float r0 = 0.f, r1 = 0.f;
  if (i0 < SIG) r0 = Pn[SIG + i0];
  if (i1 < SIG) r1 = Pn[SIG + i1];

  const int e4 = tid;
  const int q4a = e4 / 125, r125 = e4 % 125, r25 = e4 % 25, r5 = e4 % 5;
  const int e4d5 = e4 / 5, e4d25 = e4 / 25;
  const int e3 = tid;
  const int e3a = e3 / 25, e3r25 = e3 % 25, e3r5 = e3 % 5, e3d5 = e3 / 5;
  const int e2 = tid - 125;
  const int e1 = tid - 150;

  for (int s = 1; s < N_SEG; ++s) {
    if (i0 < SIG) Bs[i0] = r0;
    if (i1 < SIG) Bs[i1] = r1;
    __syncthreads();
    if (s + 1 < N_SEG) {
      const float* Pnx = Pn + (size_t)(s + 1) * SIG;
      if (i0 < SIG) r0 = Pnx[i0];
      if (i1 < SIG) r1 = Pnx[i1];
    }
    float v4 = 0.f, v3 = 0.f, v2 = 0.f, v1 = 0.f;
    if (tid < 625) {
      v4 = A[155 + e4] + Bs[155 + e4];
      v4 = fmaf(A[30 + e4d5], Bs[r5], v4);
      v4 = fmaf(A[5 + e4d25], Bs[5 + r25], v4);
      v4 = fmaf(A[q4a], Bs[30 + r125], v4);
    }
    if (tid < 125) {
      v3 = A[30 + e3] + Bs[30 + e3];
      v3 = fmaf(A[5 + e3d5], Bs[e3r5], v3);
      v3 = fmaf(A[e3a], Bs[5 + e3r25], v3);
    } else if (tid < 150) {
      v2 = A[5 + e2] + Bs[5 + e2];
      v2 = fmaf(A[e2 / 5], Bs[e2 % 5], v2);
    } else if (tid < 155) {
      v1 = A[e1] + Bs[e1];
    }
    __syncthreads();
    float* Po = Pn + (size_t)s * SIG;
    if (tid < 625) { A[155 + e4] = v4; Po[155 + e4] = v4; }
    if (tid < 125) { A[30 + e3] = v3; Po[30 + e3] = v3; }
    else if (tid < 150) { A[5 + e2] = v2; Po[5 + e2] = v2; }
    else if (tid < 155) { A[e1] = v1; Po[e1] = v1; }
  }
}

// ---------------- Signature phase C: stream + emit f16 planes (coalesced) ---
__global__ __launch_bounds__(320) void emit_kernel(
    const float* __restrict__ batch,
    const float* __restrict__ conv_w,
    const float* __restrict__ conv_b,
    const float* __restrict__ P,
    _Float16* __restrict__ c1,
    _Float16* __restrict__ c2) {
  int s = blockIdx.x;
  int n = blockIdx.y;
  int tid = threadIdx.x;

  __shared__ float S[SIG];
  __shared__ float bc[(SEG_LEN + 1) * CH];
  __shared__ float dsh[SEG_LEN][CH];
  __shared__ __align__(16) _Float16 row1[KP];
  __shared__ __align__(16) _Float16 row2[KP];

  if (s == 0) {
    for (int i = tid; i < SIG; i += 320) S[i] = 0.0f;
  } else {
    const float* Pr = P + ((size_t)n * N_SEG + (s - 1)) * SIG;
    for (int i = tid; i < SIG; i += 320) S[i] = Pr[i];
  }
  if (tid < (SEG_LEN + 1) * CH) {
    int r = s * SEG_LEN - 1 + tid / CH, ch = tid % CH;
    float v = 0.0f;
    if (r >= 0) {
      const float* a = batch + ((size_t)n * T_LEN + r) * IN_D;
      const float* w = conv_w + ch * CH;
      v = conv_b[ch];
      v = fmaf(a[0], w[0], v);
      v = fmaf(a[1], w[1], v);
      v = fmaf(a[2], w[2], v);
      v = fmaf(a[3], w[3], v);
      v = fmaf((float)(r + 1) * (1.0f / T_LEN), w[4], v);
    }
    bc[tid] = v;
  }
  if (tid < KP - SIG) {  // zero the pad tail once
    row1[SIG + tid] = (_Float16)0.0f;
    row2[SIG + tid] = (_Float16)0.0f;
  }
  __syncthreads();
  if (tid < SEG_LEN * CH) {
    int j = tid / CH, ch = tid % CH;
    dsh[j][ch] = bc[(j + 1) * CH + ch] - bc[j * CH + ch];
  }

  const int x0 = tid;
  const int x1 = tid + 320;
  const bool has1 = (tid < 305);
  const int a0i = x0 / 125, b0i = (x0 / 25) % 5, c0i = (x0 / 5) % 5, d0i = x0 % 5;
  const int a1i = x1 / 125, b1i = (x1 / 25) % 5, c1i = (x1 / 5) % 5, d1i = x1 % 5;
  const int s2_0 = x0 / 25, s3_0 = x0 / 5;
  const int s2_1 = x1 / 25, s3_1 = x1 / 5;
  const bool hasL3 = (tid < 125);
  const int ya = tid / 25, yb = (tid / 5) % 5, yc = tid % 5;
  const bool hasL2 = (tid < 25);
  const int za = tid / 5, zb = tid % 5;
  const bool hasL1 = (tid < CH);
  __syncthreads();

  for (int j = 0; j < SEG_LEN; ++j) {
    int t = s * SEG_LEN + j;
    float n4_0, n4_1 = 0.0f, n3 = 0.0f, n2 = 0.0f, n1 = 0.0f;
    {
      float tH = fmaf(0.25f, dsh[j][a0i], S[a0i]);
      tH = fmaf((1.0f / 3.0f) * dsh[j][b0i], tH, S[5 + s2_0]);
      tH = fmaf(0.5f * dsh[j][c0i], tH, S[30 + s3_0]);
      n4_0 = fmaf(dsh[j][d0i], tH, S[155 + x0]);
    }
    if (has1) {
      float tH = fmaf(0.25f, dsh[j][a1i], S[a1i]);
      tH = fmaf((1.0f / 3.0f) * dsh[j][b1i], tH, S[5 + s2_1]);
      tH = fmaf(0.5f * dsh[j][c1i], tH, S[30 + s3_1]);
      n4_1 = fmaf(dsh[j][d1i], tH, S[155 + x1]);
    }
    if (hasL3) {
      float tH = fmaf((1.0f / 3.0f), dsh[j][ya], S[ya]);
      tH = fmaf(0.5f * dsh[j][yb], tH, S[5 + ya * 5 + yb]);
      n3 = fmaf(dsh[j][yc], tH, S[30 + tid]);
    }
    if (hasL2) {
      float tH = fmaf(0.5f, dsh[j][za], S[za]);
      n2 = fmaf(dsh[j][zb], tH, S[5 + tid]);
    }
    if (hasL1) n1 = S[tid] + dsh[j][tid];
    __syncthreads();

    S[155 + x0] = n4_0;
    if (has1) S[155 + x1] = n4_1;
    if (hasL3) S[30 + tid] = n3;
    if (hasL2) S[5 + tid] = n2;
    if (hasL1) S[tid] = n1;

    float z = (t == 0) ? 0.0f : 1.0f;
    {
      float v = n4_0 * SC_L4 * z;
      _Float16 h = (_Float16)v;
      row1[155 + x0] = h; row2[155 + x0] = (_Float16)(v - (float)h);
    }
    if (has1) {
      float v = n4_1 * SC_L4 * z;
      _Float16 h = (_Float16)v;
      row1[155 + x1] = h; row2[155 + x1] = (_Float16)(v - (float)h);
    }
    if (hasL3) {
      float v = n3 * SC_L3 * z;
      _Float16 h = (_Float16)v;
      row1[30 + tid] = h; row2[30 + tid] = (_Float16)(v - (float)h);
    }
    if (hasL2) {
      float v = n2 * SC_L2 * z;
      _Float16 h = (_Float16)v;
      row1[5 + tid] = h; row2[5 + tid] = (_Float16)(v - (float)h);
    }
    if (hasL1) {
      float v = n1 * SC_L1 * z;
      _Float16 h = (_Float16)v;
      row1[tid] = h; row2[tid] = (_Float16)(v - (float)h);
    }
    __syncthreads();

    size_t base = ((size_t)n * T_LEN + t) * KP;
    if (tid < 100) {
      *(float4*)(c1 + base + tid * 8) = *(const float4*)&row1[tid * 8];
    } else if (tid < 200) {
      int c = tid - 100;
      *(float4*)(c2 + base + c * 8) = *(const float4*)&row2[c * 8];
    }
  }
}

// ---------------- W plane conversion (scaled, padded to 896x800) -------------
__global__ __launch_bounds__(256) void wconv_kernel(
    const float* __restrict__ W,
    _Float16* __restrict__ w1,
    _Float16* __restrict__ w2) {
  int idx = blockIdx.x * blockDim.x + threadIdx.x;
  if (idx >= 896 * KP) return;
  int nn = idx / KP, k = idx % KP;
  float v = 0.0f;
  if (nn < SIG && k < SIG) {
    float sc = (k < 5) ? 1.0f : (k < 30) ? 4.0f : (k < 155) ? 16.0f : 64.0f;
    v = W[(size_t)nn * SIG + k] * sc;
  }
  _Float16 h = (_Float16)v;
  w1[idx] = h;
  w2[idx] = (_Float16)(v - (float)h);
}

// ---------------- MFMA GEMM: out = tanh((c1+c2)*(w1+w2)^T + b) ---------------
// 256x128 block tile, 8 waves (4m x 2n), per-wave 64x64 = 4x4 of 16x16x32_f16,
// 3 products (hi*hi, hi*lo, lo*hi).
// Schedule (round 2): 4 quadrant-phases per K-step with reads distributed INTO
// the MFMA regions so the LDS pipe and matrix pipe co-schedule (round-1 had
// lumpy read-only / MFMA-only bursts -> serialized, MfmaUtil 32%).
//   [VMCNT(6); BAR]  regionA: q0 reads (a01,b01) + 2 stages
//   [BAR]            regionB: b23+a23 reads || 12 MFMA (q0) + 2 stages
//   [BAR]            regionC: 24 MFMA (q1 lgkm(4), q2 lgkm(0)) + 2 B-stages
//   [BAR]            regionD: 12 MFMA (q3)
// Counted vmcnt(6): next tile's 6 loads ride across all barriers (3 LDS bufs,
// prefetch depth 2). XCD-bijective swizzle keeps the 7 n-siblings of each
// m-tile on one XCD (FETCH 935->231 MB measured).
__global__ __launch_bounds__(512, 2) void gemm_mfma(
    const _Float16* __restrict__ A1p, const _Float16* __restrict__ A2p,
    const _Float16* __restrict__ B1p, const _Float16* __restrict__ B2p,
    const float* __restrict__ bias, float* __restrict__ out) {
  __shared__ _Float16 Al[3][2][256 * 32];  // [buf][plane] : 96 KB
  __shared__ _Float16 Bl[3][2][128 * 32];  // [buf][plane] : 48 KB

  int tid = threadIdx.x;
  int lane = tid & 63, wid = tid >> 6;
  int wm = wid >> 1, wn = wid & 1;

  int b = blockIdx.x;
  int xcd = b & 7, sidx = b >> 3;
  int mt = (sidx / 7) * 8 + xcd;
  int nt = sidx % 7;
  int m0 = mt * 256;
  int n0 = nt * 128;

  f32x4 acc[4][4];
#pragma unroll
  for (int i = 0; i < 4; ++i)
#pragma unroll
    for (int j = 0; j < 4; ++j) acc[i][j] = (f32x4){0.f, 0.f, 0.f, 0.f};

  int sr = lane >> 2, scn = lane & 3;
  int swst = (sr ^ (sr >> 2)) & 3;
  int qg = scn ^ swst;          // pre-swizzled global chunk (LDS stays linear)
  int fr = lane & 15, fq = lane >> 4;
  int swf = (fr ^ (fr >> 2)) & 3;
  int fchunk = fq ^ swf;        // matching read-side swizzle

  auto stageA = [&](int kb, int buf, int i) {
    int k0 = kb * 32;
    int linear = wid * 4 + i;          // 0..31
    int plane = linear >> 4, grp = linear & 15;
    size_t g = (size_t)(m0 + grp * 16 + sr) * KP + k0 + qg * 8;
    const _Float16* src = (plane ? A2p : A1p) + g;
    __builtin_amdgcn_global_load_lds((as1cp)src, (as3p)(&Al[buf][plane][grp * 512]), 16, 0, 0);
  };
  auto stageB = [&](int kb, int buf, int i) {
    int k0 = kb * 32;
    int linear = wid * 2 + i;          // 0..15
    int plane = linear >> 3, grp = linear & 7;
    size_t g = (size_t)(n0 + grp * 16 + sr) * KP + k0 + qg * 8;
    const _Float16* src = (plane ? B2p : B1p) + g;
    __builtin_amdgcn_global_load_lds((as1cp)src, (as3p)(&Bl[buf][plane][grp * 512]), 16, 0, 0);
  };

  // prologue: tiles 0 and 1 in flight (12 loads/thread)
#pragma unroll
  for (int i = 0; i < 4; ++i) stageA(0, 0, i);
#pragma unroll
  for (int i = 0; i < 2; ++i) stageB(0, 0, i);
#pragma unroll
  for (int i = 0; i < 4; ++i) stageA(1, 1, i);
#pragma unroll
  for (int i = 0; i < 2; ++i) stageB(1, 1, i);

  f16x8 a1f[4], a2f[4], b1f[4], b2f[4];
  int cur = 0;

#define READ_A(tm)                                                     \
  {                                                                    \
    int off = (wm * 64 + (tm) * 16 + fr) * 32 + fchunk * 8;            \
    a1f[tm] = *(const f16x8*)&Al[cur][0][off];                         \
    a2f[tm] = *(const f16x8*)&Al[cur][1][off];                         \
  }
#define READ_B(tn)                                                     \
  {                                                                    \
    int off = (wn * 64 + (tn) * 16 + fr) * 32 + fchunk * 8;            \
    b1f[tn] = *(const f16x8*)&Bl[cur][0][off];                         \
    b2f[tn] = *(const f16x8*)&Bl[cur][1][off];                         \
  }
#define MFMA3(tm, tn)                                                                               \
  acc[tm][tn] = __builtin_amdgcn_mfma_f32_16x16x32_f16(a1f[tm], b1f[tn], acc[tm][tn], 0, 0, 0);     \
  acc[tm][tn] = __builtin_amdgcn_mfma_f32_16x16x32_f16(a1f[tm], b2f[tn], acc[tm][tn], 0, 0, 0);     \
  acc[tm][tn] = __builtin_amdgcn_mfma_f32_16x16x32_f16(a2f[tm], b1f[tn], acc[tm][tn], 0, 0, 0);

#pragma unroll 1
  for (int kb = 0; kb < 25; ++kb) {
    int nx = cur + 2; if (nx >= 3) nx -= 3;
    bool pf = (kb + 2 < 25);
    // counted wait: tile kb done, tile kb+1's 6 loads stay in flight
    if (kb < 24) { VMCNT(6); } else { VMCNT(0); }
    __builtin_amdgcn_s_barrier();
    __builtin_amdgcn_sched_barrier(0);
    // region A: q0 frags + 2 A-stages (read-only; buffer just published)
    READ_A(0); READ_A(1);
    READ_B(0); READ_B(1);
    if (pf) { stageA(kb + 2, nx, 0); stageA(kb + 2, nx, 1); }
    __builtin_amdgcn_s_barrier();
    __builtin_amdgcn_sched_barrier(0);
    // region B: reads for q1/q2 issue under q0's MFMA (lgkmcnt(8) before q0)
    READ_B(2); READ_B(3);
    READ_A(2); READ_A(3);
    if (pf) { stageA(kb + 2, nx, 2); stageA(kb + 2, nx, 3); }
    __builtin_amdgcn_s_setprio(1);
    MFMA3(0, 0); MFMA3(0, 1); MFMA3(1, 0); MFMA3(1, 1);
    __builtin_amdgcn_s_setprio(0);
    __builtin_amdgcn_s_barrier();
    __builtin_amdgcn_sched_barrier(0);
    // region C: q1 (waits b23, lgkm(4)) then q2 (waits a23, lgkm(0))
    if (pf) { stageB(kb + 2, nx, 0); stageB(kb + 2, nx, 1); }
    __builtin_amdgcn_s_setprio(1);
    MFMA3(0, 2); MFMA3(0, 3); MFMA3(1, 2); MFMA3(1, 3);
    MFMA3(2, 0); MFMA3(2, 1); MFMA3(3, 0); MFMA3(3, 1);
    __builtin_amdgcn_s_setprio(0);
    __builtin_amdgcn_s_barrier();
    __builtin_amdgcn_sched_barrier(0);
    // region D: q3 (all frags resident)
    __builtin_amdgcn_s_setprio(1);
    MFMA3(2, 2); MFMA3(2, 3); MFMA3(3, 2); MFMA3(3, 3);
    __builtin_amdgcn_s_setprio(0);
    cur = cur + 1; if (cur >= 3) cur -= 3;
  }
#undef READ_A
#undef READ_B
#undef MFMA3
  __syncthreads();  // all frag reads done; LDS reusable for epilogue

  // epilogue: bias + fast tanh, per-wave LDS transpose, float4 stores
  float* ep = (float*)(&Al[0][0][0]) + wid * 2112;  // 32x66 f32 per wave

  float bv[4];
#pragma unroll
  for (int tn = 0; tn < 4; ++tn) {
    int nn = n0 + wn * 64 + tn * 16 + fr;
    bv[tn] = (nn < SIG) ? bias[nn] : 0.0f;
  }
#pragma unroll
  for (int h = 0; h < 2; ++h) {
#pragma unroll
    for (int tm2 = 0; tm2 < 2; ++tm2) {
      int tm = h * 2 + tm2;
#pragma unroll
      for (int tn = 0; tn < 4; ++tn) {
#pragma unroll
        for (int r = 0; r < 4; ++r) {
          int lr = tm2 * 16 + fq * 4 + r;  // 0..31
          int lc = tn * 16 + fr;           // 0..63
          ep[lr * 66 + lc] = fast_tanh(acc[tm][tn][r] + bv[tn]);
        }
      }
    }
    // wave-synchronous readout: 32 rows x 64 cols, float4 per 4 cols
#pragma unroll
    for (int p = 0; p < 2; ++p) {
      int lr = lane & 31;
      int ck = (lane >> 5) * 2 + p;  // 0..3 (16-col chunk)
      int gm = m0 + wm * 64 + h * 32 + lr;
      int gc0 = n0 + wn * 64 + ck * 16;
#pragma unroll
      for (int q = 0; q < 4; ++q) {
        int col = gc0 + q * 4;
        if (col + 3 < SIG) {
          *(float4*)(out + (size_t)gm * SIG + col) =
              *(const float4*)&ep[lr * 66 + ck * 16 + q * 4];
        } else if (col < SIG) {
#pragma unroll
          for (int e = 0; e < 4; ++e) {
            int c2 = col + e;
            if (c2 < SIG) out[(size_t)gm * SIG + c2] = ep[lr * 66 + ck * 16 + q * 4 + e];
          }
        }
      }
    }
  }
}

// ================= FALLBACK PATH (round-1, fp32) =============================
__global__ __launch_bounds__(320) void sig_kernel_fb(
    const float* __restrict__ b_in, float* __restrict__ c_out) {
  int n = blockIdx.x;
  int tid = threadIdx.x;
  __shared__ float S[SIG];
  __shared__ float bc[64 * CH];
  __shared__ float dsh[CH];
  __shared__ float pb[CH];
  for (int i = tid; i < SIG; i += 320) S[i] = 0.0f;
  if (tid < CH) pb[tid] = 0.0f;
  const float* bn = b_in + (size_t)n * T_LEN * CH;
  float* cn = c_out + (size_t)n * T_LEN * SIG;
  const int x0 = tid, x1 = tid + 320;
  const bool has1 = (tid < 305);
  const int a0i = x0 / 125, b0i = (x0 / 25) % 5, c0i = (x0 / 5) % 5, d0i = x0 % 5;
  const int a1i = x1 / 125, b1i = (x1 / 25) % 5, c1i = (x1 / 5) % 5, d1i = x1 % 5;
  const int s2_0 = x0 / 25, s3_0 = x0 / 5, s2_1 = x1 / 25, s3_1 = x1 / 5;
  const bool hasL3 = (tid < 125);
  const int ya = tid / 25, yb = (tid / 5) % 5, yc = tid % 5;
  const bool hasL2 = (tid < 25);
  const int za = tid / 5, zb = tid % 5;
  const bool hasL1 = (tid < CH);
  for (int t = 0; t < T_LEN; ++t) {
    if ((t & 63) == 0) {
      __syncthreads();
      bc[tid] = bn[t * CH + tid];
      __syncthreads();
    }
    if (tid < CH) {
      float cur = bc[(t & 63) * CH + tid];
      dsh[tid] = cur - pb[tid];
      pb[tid] = cur;
    }
    __syncthreads();
    float n4_0, n4_1 = 0.0f, n3 = 0.0f, n2 = 0.0f, n1 = 0.0f;
    {
      float tH = fmaf(0.25f, dsh[a0i], S[a0i]);
      tH = fmaf((1.0f / 3.0f) * dsh[b0i], tH, S[5 + s2_0]);
      tH = fmaf(0.5f * dsh[c0i], tH, S[30 + s3_0]);
      n4_0 = fmaf(dsh[d0i], tH, S[155 + x0]);
    }
    if (has1) {
      float tH = fmaf(0.25f, dsh[a1i], S[a1i]);
      tH = fmaf((1.0f / 3.0f) * dsh[b1i], tH, S[5 + s2_1]);
      tH = fmaf(0.5f * dsh[c1i], tH, S[30 + s3_1]);
      n4_1 = fmaf(dsh[d1i], tH, S[155 + x1]);
    }
    if (hasL3) {
      float tH = fmaf((1.0f / 3.0f), dsh[ya], S[ya]);
      tH = fmaf(0.5f * dsh[yb], tH, S[5 + ya * 5 + yb]);
      n3 = fmaf(dsh[yc], tH, S[30 + tid]);
    }
    if (hasL2) {
      float tH = fmaf(0.5f, dsh[za], S[za]);
      n2 = fmaf(dsh[zb], tH, S[5 + tid]);
    }
    if (hasL1) n1 = S[tid] + dsh[tid];
    __syncthreads();
    S[155 + x0] = n4_0;
    if (has1) S[155 + x1] = n4_1;
    if (hasL3) S[30 + tid] = n3;
    if (hasL2) S[5 + tid] = n2;
    if (hasL1) S[tid] = n1;
    float* crow = cn + (size_t)t * SIG;
    float z = (t == 0) ? 0.0f : 1.0f;
    crow[155 + x0] = n4_0 * z;
    if (has1) crow[155 + x1] = n4_1 * z;
    if (hasL3) crow[30 + tid] = n3 * z;
    if (hasL2) crow[5 + tid] = n2 * z;
    if (hasL1) crow[tid] = n1 * z;
    __syncthreads();
  }
}

#define BM 256
#define BN 64
#define BK 16
__global__ __launch_bounds__(256) void gemm_tanh_fb(
    const float* __restrict__ Cmat, const float* __restrict__ W,
    const float* __restrict__ bias, float* __restrict__ out) {
  __shared__ float As[BK][BM + 4];
  __shared__ float Ws[BK][BN + 4];
  int tid = threadIdx.x;
  int tx = tid & 7, ty = tid >> 3;
  int m0 = blockIdx.x * BM, n0 = blockIdx.y * BN;
  float acc[8][8];
#pragma unroll
  for (int i = 0; i < 8; ++i)
#pragma unroll
    for (int j = 0; j < 8; ++j) acc[i][j] = 0.0f;
  for (int kb = 0; kb < SIG; kb += BK) {
    __syncthreads();
#pragma unroll
    for (int p = 0; p < 4; ++p) {
      int id = tid + p * 256;
      int row = id >> 2, kg = (id & 3) * 4, gk = kb + kg;
      float4 v = make_float4(0.f, 0.f, 0.f, 0.f);
      if (gk < SIG) v = *(const float4*)(Cmat + (size_t)(m0 + row) * SIG + gk);
      As[kg + 0][row] = v.x; As[kg + 1][row] = v.y;
      As[kg + 2][row] = v.z; As[kg + 3][row] = v.w;
    }
    {
      int row = tid >> 2, kg = (tid & 3) * 4, gk = kb + kg, wr = n0 + row;
      float4 v = make_float4(0.f, 0.f, 0.f, 0.f);
      if (gk < SIG && wr < SIG) v = *(const float4*)(W + (size_t)wr * SIG + gk);
      Ws[kg + 0][row] = v.x; Ws[kg + 1][row] = v.y;
      Ws[kg + 2][row] = v.z; Ws[kg + 3][row] = v.w;
    }
    __syncthreads();
#pragma unroll
    for (int k = 0; k < BK; ++k) {
      float af[8], wf[8];
      *(float4*)&af[0] = *(const float4*)&As[k][ty * 8];
      *(float4*)&af[4] = *(const float4*)&As[k][ty * 8 + 4];
      *(float4*)&wf[0] = *(const float4*)&Ws[k][tx * 8];
      *(float4*)&wf[4] = *(const float4*)&Ws[k][tx * 8 + 4];
#pragma unroll
      for (int i = 0; i < 8; ++i)
#pragma unroll
        for (int j = 0; j < 8; ++j) acc[i][j] = fmaf(af[i], wf[j], acc[i][j]);
    }
  }
#pragma unroll
  for (int i = 0; i < 8; ++i) {
    int m = m0 + ty * 8 + i;
    float* orow = out + (size_t)m * SIG;
#pragma unroll
    for (int jj = 0; jj < 8; jj += 4) {
      int col = n0 + tx * 8 + jj;
      if (col < SIG) {
        float4 r;
        r.x = tanhf(acc[i][jj + 0] + bias[col + 0]);
        r.y = tanhf(acc[i][jj + 1] + bias[col + 1]);
        r.z = tanhf(acc[i][jj + 2] + bias[col + 2]);
        r.w = tanhf(acc[i][jj + 3] + bias[col + 3]);
        *(float4*)(orow + col) = r;
      }
    }
  }
}

// ---------------- launch ----------------
extern "C" void kernel_launch(void* const* d_in, const int* in_sizes, int n_in,
                              void* d_out, int out_size, void* d_ws, size_t ws_size,
                              hipStream_t stream) {
  const float* batch = (const float*)d_in[0];
  const float* conv_w = (const float*)d_in[1];
  const float* conv_b = (const float*)d_in[2];
  const float* lin_w = (const float*)d_in[3];
  const float* lin_b = (const float*)d_in[4];
  float* out = (float*)d_out;

  const size_t plane_elems = (size_t)N_B * T_LEN * KP;        // 52,428,800
  const size_t wplane_elems = (size_t)896 * KP;               // 716,800
  const size_t P_elems = (size_t)N_B * N_SEG * SIG;           // 3,194,880
  const size_t bp_elems = (size_t)N_B * T_LEN * CH;           // 327,680
  const size_t need_big = 2 * plane_elems * sizeof(_Float16) +
                          2 * wplane_elems * sizeof(_Float16) +
                          P_elems * sizeof(float);

  if (ws_size >= need_big) {
    _Float16* c1 = (_Float16*)d_ws;
    _Float16* c2 = c1 + plane_elems;
    _Float16* w1 = c2 + plane_elems;
    _Float16* w2 = w1 + wplane_elems;
    float* P = (float*)(w2 + wplane_elems);

    wconv_kernel<<<dim3((896 * KP + 255) / 256), dim3(256), 0, stream>>>(
        lin_w, w1, w2);
    seg_kernel<<<dim3(N_SEG, N_B), dim3(320), 0, stream>>>(batch, conv_w, conv_b, P);
    prefix_kernel<<<dim3(N_B), dim3(640), 0, stream>>>(P);
    emit_kernel<<<dim3(N_SEG, N_B), dim3(320), 0, stream>>>(
        batch, conv_w, conv_b, P, c1, c2);
    gemm_mfma<<<dim3(1792), dim3(512), 0, stream>>>(c1, c2, w1, w2, lin_b, out);
  } else {
    float* b_path = (float*)d_ws;
    float* c_sig = (float*)d_ws + bp_elems;
    conv_kernel<<<dim3((N_B * T_LEN + 255) / 256), dim3(256), 0, stream>>>(
        batch, conv_w, conv_b, b_path);
    sig_kernel_fb<<<dim3(N_B), dim3(320), 0, stream>>>(b_path, c_sig);
    gemm_tanh_fb<<<dim3((N_B * T_LEN) / BM, (SIG + BN - 1) / BN), dim3(256), 0, stream>>>(
        c_sig, lin_w, lin_b, out);
  }
}